// Round 11
// baseline (40769.843 us; speedup 1.0000x reference)
//
#include <hip/hip_runtime.h>

// SingleLayerRNN — Round 11: single persistent kernel, per-group spin barriers.
//
// FROZEN arithmetic (R8, absmax=0.0): per output (b,j):
//   cx0 = FMA chain k=0..511 of x[b,k]*Wih[k,j] (ascending, single acc)
//   cx1 = chain k=512..1023; ch0/ch1 = same over h,Whh
//   s = (cx0+cx1)+(ch0+ch1); h' = tanh_T2(s) [XLA fast-tanh FMA form]
//
// Structure: grid 1024 x 256 thr. Block = (mat2, half2, b8, jl8); each thread
// owns ONE 512-chain per step. Group g = bid&7 owns rows [8g,8g+8) — rows are
// independent across groups, so barriers are group-scoped (128 blocks).
// Pipeline: mat0 computes cx(t+1) while mat1 computes ch(t). h double-buffered
// in d_ws; per-group monotonic arrival counters, memset to 0 each call.

#define TSTEPS 512
#define BATCH  64
#define HID    1024
#define NELEM  65536
#define NBLK   1024
#define GBLK   128      // blocks per group (NBLK/8)

__device__ __forceinline__ float tanh_T2(float x) {
#pragma clang fp contract(off)
    const float C = 7.99881172180175781f;
    float ax = fabsf(x);
    float xc = fminf(fmaxf(x, -C), C);
    float x2 = xc * xc;
    float num = -2.76076847742355e-16f;
    num = __builtin_fmaf(x2, num, 2.00018790482477e-13f);
    num = __builtin_fmaf(x2, num, -8.60467152213735e-11f);
    num = __builtin_fmaf(x2, num, 5.12229709037114e-08f);
    num = __builtin_fmaf(x2, num, 1.48572235717979e-05f);
    num = __builtin_fmaf(x2, num, 6.37261928875436e-04f);
    num = __builtin_fmaf(x2, num, 4.89352455891786e-03f);
    num = xc * num;
    float den = 1.19825839466702e-06f;
    den = __builtin_fmaf(x2, den, 1.18534705686654e-04f);
    den = __builtin_fmaf(x2, den, 2.26843463243900e-03f);
    den = __builtin_fmaf(x2, den, 4.89352518554385e-03f);
    float r = num / den;
    return (ax < 0.0004f) ? x : r;
}

__global__ __launch_bounds__(256, 4) void rnn_persist(
    const float* __restrict__ x,     // [512][64][1024]
    const float* __restrict__ Wih,   // [1024(k)][1024(j)]
    const float* __restrict__ Whh,
    float* __restrict__ h0,          // ws ping
    float* __restrict__ h1,          // ws pong
    unsigned int* __restrict__ cnt,  // 8 groups x 32 uints (128B apart)
    float* __restrict__ out)         // d_out [64][1024]
{
#pragma clang fp contract(off)
    const int g     = blockIdx.x & 7;
    const int chunk = blockIdx.x >> 3;        // 0..127
    const int tid   = threadIdx.x;
    const int jl    = tid & 7;
    const int b     = (tid >> 3) & 7;
    const int half  = (tid >> 6) & 1;
    const int mat   = tid >> 7;               // wave-uniform
    const int j     = chunk * 8 + jl;
    const int brow  = g * 8 + b;
    const int k0    = half * 512;

    __shared__ float pcx[2][2][8][8];         // [parity][half][b][jl]
    __shared__ float pch[2][8][8];

    float* hb[2] = { h0, h1 };
    unsigned int* mycnt = cnt + (size_t)g * 32;

    // prologue: cx(0)
    if (mat == 0) {
        const float* xr = x + (size_t)brow * HID + k0;
        const float* wp = Wih + (size_t)k0 * HID + j;
        float acc = 0.0f;
        #pragma unroll 16
        for (int k = 0; k < 512; ++k)
            acc = __builtin_fmaf(xr[k], wp[(size_t)k * HID], acc);
        pcx[0][half][b][jl] = acc;
    }
    __syncthreads();

    for (int t = 0; t < TSTEPS; ++t) {
        // ---- wait: h_{t-1} published by all 128 blocks of this group ----
        if (t > 0) {
            if (tid == 0) {
                while (__hip_atomic_load(mycnt, __ATOMIC_RELAXED,
                                         __HIP_MEMORY_SCOPE_AGENT)
                       < (unsigned)(GBLK * t))
                    __builtin_amdgcn_s_sleep(1);
                __builtin_amdgcn_fence(__ATOMIC_ACQUIRE, "agent");
            }
            __syncthreads();
        }

        if (mat == 1) {
            // ch(t) over h_{t-1}
            float acc = 0.0f;
            if (t > 0) {
                const float* hr = hb[(t - 1) & 1] + (size_t)brow * HID + k0;
                const float* wp = Whh + (size_t)k0 * HID + j;
                #pragma unroll 16
                for (int k = 0; k < 512; ++k)
                    acc = __builtin_fmaf(hr[k], wp[(size_t)k * HID], acc);
            }
            pch[half][b][jl] = acc;
        } else if (t + 1 < TSTEPS) {
            // cx(t+1) — pipelined ahead
            const float* xr = x + (size_t)(t + 1) * NELEM + (size_t)brow * HID + k0;
            const float* wp = Wih + (size_t)k0 * HID + j;
            float acc = 0.0f;
            #pragma unroll 16
            for (int k = 0; k < 512; ++k)
                acc = __builtin_fmaf(xr[k], wp[(size_t)k * HID], acc);
            pcx[(t + 1) & 1][half][b][jl] = acc;
        }
        __syncthreads();

        // ---- combine (exact frozen order) + store h_t ----
        if (tid < 64) {
            const int cb = tid >> 3;
            const int cj = tid & 7;
            const float dotX = pcx[t & 1][0][cb][cj] + pcx[t & 1][1][cb][cj];
            const float dotH = pch[0][cb][cj] + pch[1][cb][cj];
            const float hv = tanh_T2(dotX + dotH);
            const size_t o = (size_t)(g * 8 + cb) * HID + (size_t)chunk * 8 + cj;
            if (t + 1 < TSTEPS) hb[t & 1][o] = hv;
            else                out[o] = hv;
        }
        __syncthreads();   // drains h stores (vmcnt 0) for every thread

        // ---- publish ----
        if (t + 1 < TSTEPS && tid == 0) {
            __builtin_amdgcn_fence(__ATOMIC_RELEASE, "agent");  // L2 writeback
            __hip_atomic_fetch_add(mycnt, 1u, __ATOMIC_RELAXED,
                                   __HIP_MEMORY_SCOPE_AGENT);
        }
    }
}

__global__ __launch_bounds__(256) void sentinel(float* o, float c) {
    const int tid = blockIdx.x * 256 + threadIdx.x;
    if (tid < NELEM) o[tid] = c;
}

extern "C" void kernel_launch(void* const* d_in, const int* in_sizes, int n_in,
                              void* d_out, int out_size, void* d_ws, size_t ws_size,
                              hipStream_t stream) {
    const float* x   = (const float*)d_in[0];
    const float* Wih = (const float*)d_in[1];
    const float* Whh = (const float*)d_in[2];
    float* out = (float*)d_out;

    const size_t need = (size_t)2 * NELEM * sizeof(float) + 8 * 32 * sizeof(unsigned int);
    if (ws_size < need) {   // R7 proved ws >= 8MB; guard anyway (err 1.45 marker)
        sentinel<<<dim3(NELEM / 256), dim3(256), 0, stream>>>(out, 0.45f);
        return;
    }
    float* h0 = (float*)d_ws;
    float* h1 = h0 + NELEM;
    unsigned int* cnt = (unsigned int*)(h1 + NELEM);

    hipMemsetAsync(cnt, 0, 8 * 32 * sizeof(unsigned int), stream);
    rnn_persist<<<dim3(NBLK), dim3(256), 0, stream>>>(
        x, Wih, Whh, h0, h1, cnt, out);
}

// Round 12
// 21175.294 us; speedup vs baseline: 1.9253x; 1.9253x over previous
//
#include <hip/hip_runtime.h>

// SingleLayerRNN — Round 12: persistent kernel, j-sliced XCD partition,
// L2-preserving coherence (bypass h, no acquire fences).
//
// FROZEN arithmetic (R8, absmax=0.0):
//   cx0 = FMA chain k=0..511 of x[b,k]*Wih[k,j] (ascending, single acc)
//   cx1 = chain k=512..1023; ch0/ch1 = same over h,Whh
//   s = (cx0+cx1)+(ch0+ch1); h' = tanh_T2(s)  [XLA fast-tanh FMA form]
//
// Counter-driven redesign vs R11 (VALUBusy 12%, FETCH 33MB/step = W thrash):
//  - slice = bid&7 owns 128 j cols -> per-XCD W slice 1MB, L2-resident.
//  - h via system-scope relaxed atomics (L1/L2 bypass, IF-coherent): no
//    buffer_inv anywhere -> W/x stay cached. Release add publishes.
//  - WT[j][k] (R10-verified transpose) -> float4 W loads, 128 insts/wave/step.
//  - grid 512 x 256thr, 67.8KB LDS -> exactly 2 blocks/CU, all co-resident.

#define TSTEPS 512
#define BATCH  64
#define HID    1024
#define NELEM  65536
#define LROW   1028     // LDS row stride (floats): 16B-aligned, bank-spread

__device__ __forceinline__ float tanh_T2(float x) {
#pragma clang fp contract(off)
    const float C = 7.99881172180175781f;
    float ax = fabsf(x);
    float xc = fminf(fmaxf(x, -C), C);
    float x2 = xc * xc;
    float num = -2.76076847742355e-16f;
    num = __builtin_fmaf(x2, num, 2.00018790482477e-13f);
    num = __builtin_fmaf(x2, num, -8.60467152213735e-11f);
    num = __builtin_fmaf(x2, num, 5.12229709037114e-08f);
    num = __builtin_fmaf(x2, num, 1.48572235717979e-05f);
    num = __builtin_fmaf(x2, num, 6.37261928875436e-04f);
    num = __builtin_fmaf(x2, num, 4.89352455891786e-03f);
    num = xc * num;
    float den = 1.19825839466702e-06f;
    den = __builtin_fmaf(x2, den, 1.18534705686654e-04f);
    den = __builtin_fmaf(x2, den, 2.26843463243900e-03f);
    den = __builtin_fmaf(x2, den, 4.89352518554385e-03f);
    float r = num / den;
    return (ax < 0.0004f) ? x : r;
}

// W [k][j] -> WT [j][k]  (bit-exact data movement; verified in R10)
__global__ __launch_bounds__(256) void transpose_w(const float* __restrict__ W,
                                                   float* __restrict__ WT) {
    __shared__ float tile[64][65];
    const int c0 = blockIdx.x * 64;    // j tile
    const int r0 = blockIdx.y * 64;    // k tile
    const int tx = threadIdx.x & 63;
    const int ty = threadIdx.x >> 6;
    #pragma unroll
    for (int r = 0; r < 16; ++r) {
        const int rr = r * 4 + ty;
        tile[rr][tx] = W[(size_t)(r0 + rr) * HID + c0 + tx];
    }
    __syncthreads();
    #pragma unroll
    for (int r = 0; r < 16; ++r) {
        const int rr = r * 4 + ty;
        WT[(size_t)(c0 + rr) * HID + r0 + tx] = tile[tx][rr];
    }
}

__global__ __launch_bounds__(256, 2) void rnn_persist2(
    const float* __restrict__ x,      // [512][64][1024]
    const float* __restrict__ WTih,   // [j][k]
    const float* __restrict__ WThh,   // [j][k]
    float* __restrict__ hb0,
    float* __restrict__ hb1,
    unsigned int* __restrict__ cnt,   // 8 counters, 128B apart
    float* __restrict__ out)
{
#pragma clang fp contract(off)
    __shared__ float lds_x[8 * LROW];
    __shared__ float lds_h[8 * LROW];
    __shared__ float pl[4][8][16];    // [mat*2+half][b][j]

    const int slice  = blockIdx.x & 7;     // j-slice (~XCD)
    const int wid    = blockIdx.x >> 3;    // 0..63 within slice
    const int bchunk = wid >> 3;           // 0..7 (8 batch rows each)
    const int jchunk = wid & 7;            // 0..7 (16 j cols each)
    const int tid  = threadIdx.x;
    const int jl   = tid & 15;
    const int bp   = (tid >> 4) & 3;
    const int half = (tid >> 6) & 1;
    const int mat  = tid >> 7;             // wave-uniform
    const int jglob = slice * 128 + jchunk * 16 + jl;
    const int b0 = 2 * bp;

    const float* wrow = ((mat == 0) ? WTih : WThh)
                      + (size_t)jglob * HID + half * 512;
    float* hb[2] = { hb0, hb1 };

    for (int t = 0; t < TSTEPS; ++t) {
        // ---- wait until all 512 blocks published h_t (t>=1) ----
        if (t > 0) {
            if (tid < 8) {
                const unsigned target = 64u * (unsigned)t;
                while (__hip_atomic_load(&cnt[tid * 32], __ATOMIC_RELAXED,
                                         __HIP_MEMORY_SCOPE_SYSTEM) < target)
                    __builtin_amdgcn_s_sleep(2);
            }
            __syncthreads();
        }

        // ---- stage x_t (cacheable) and h_t (bypass) into LDS ----
        {
            const float* xsrc = x + (size_t)t * NELEM
                              + (size_t)(bchunk * 8) * HID;
            float4 xv[8];
            #pragma unroll
            for (int u = 0; u < 8; ++u) {
                const int i = tid + u * 256;            // float4 id 0..2047
                const int r = i >> 8, c4 = i & 255;
                xv[u] = ((const float4*)(xsrc + (size_t)r * HID))[c4];
            }
            #pragma unroll
            for (int u = 0; u < 8; ++u) {
                const int i = tid + u * 256;
                const int r = i >> 8, c4 = i & 255;
                *(float4*)&lds_x[r * LROW + c4 * 4] = xv[u];
            }
        }
        if (t > 0) {
            const float* hsrc = hb[t & 1] + (size_t)(bchunk * 8) * HID;
            for (int blk = 0; blk < 4; ++blk) {
                float hv[8];
                #pragma unroll
                for (int u = 0; u < 8; ++u) {
                    const int i = tid + (blk * 8 + u) * 256;   // dword 0..8191
                    const int r = i >> 10, k = i & 1023;
                    hv[u] = __hip_atomic_load(&hsrc[(size_t)r * HID + k],
                                              __ATOMIC_RELAXED,
                                              __HIP_MEMORY_SCOPE_SYSTEM);
                }
                #pragma unroll
                for (int u = 0; u < 8; ++u) {
                    const int i = tid + (blk * 8 + u) * 256;
                    const int r = i >> 10, k = i & 1023;
                    lds_h[r * LROW + k] = hv[u];
                }
            }
        }
        __syncthreads();

        // ---- chains (frozen order; two b-rows share each W value) ----
        float acc0 = 0.0f, acc1 = 0.0f;
        if (mat == 0 || t > 0) {
            const float* base = (mat == 0) ? lds_x : lds_h;
            const float* oa = base + b0 * LROW;
            const float* ob = base + (b0 + 1) * LROW;
            const float4* w4 = (const float4*)wrow;
            const int kbase = half * 512;
            #pragma unroll 4
            for (int kq = 0; kq < 128; ++kq) {
                const float4 w = w4[kq];
                const int k = kbase + kq * 4;
                acc0 = __builtin_fmaf(oa[k + 0], w.x, acc0);
                acc1 = __builtin_fmaf(ob[k + 0], w.x, acc1);
                acc0 = __builtin_fmaf(oa[k + 1], w.y, acc0);
                acc1 = __builtin_fmaf(ob[k + 1], w.y, acc1);
                acc0 = __builtin_fmaf(oa[k + 2], w.z, acc0);
                acc1 = __builtin_fmaf(ob[k + 2], w.z, acc1);
                acc0 = __builtin_fmaf(oa[k + 3], w.w, acc0);
                acc1 = __builtin_fmaf(ob[k + 3], w.w, acc1);
            }
        }
        pl[mat * 2 + half][b0][jl]     = acc0;
        pl[mat * 2 + half][b0 + 1][jl] = acc1;
        __syncthreads();

        // ---- combine (frozen order) + publish h_{t+1} ----
        if (tid < 128) {
            const int b = tid >> 4, j = tid & 15;
            const float dotX = pl[0][b][j] + pl[1][b][j];   // cx0 + cx1
            const float dotH = pl[2][b][j] + pl[3][b][j];   // ch0 + ch1
            const float hv = tanh_T2(dotX + dotH);
            const size_t o = (size_t)(bchunk * 8 + b) * HID
                           + (size_t)slice * 128 + (size_t)jchunk * 16 + j;
            if (t + 1 < TSTEPS)
                __hip_atomic_store(&hb[(t + 1) & 1][o], hv, __ATOMIC_RELAXED,
                                   __HIP_MEMORY_SCOPE_SYSTEM);
            else
                out[o] = hv;
        }
        __syncthreads();   // all waves drained their stores before arrival

        if (t + 1 < TSTEPS && tid == 0)
            __hip_atomic_fetch_add(&cnt[slice * 32], 1u, __ATOMIC_RELEASE,
                                   __HIP_MEMORY_SCOPE_SYSTEM);
    }
}

// ---- proven fallback (R8): 512 launches, 512KB ws ----
__global__ __launch_bounds__(256) void rnn_step_r8(
    const float* __restrict__ xt, const float* __restrict__ Wih,
    const float* __restrict__ Whh, const float* __restrict__ hin,
    float* __restrict__ hout)
{
#pragma clang fp contract(off)
    __shared__ float xs[4 * HID];
    __shared__ float hs[4 * HID];
    const int jb = blockIdx.x * 64;
    const int ib = blockIdx.y * 4;
    for (int idx = threadIdx.x; idx < 4 * HID; idx += 256) {
        xs[idx] = xt[ib * HID + idx];
        hs[idx] = hin ? hin[ib * HID + idx] : 0.0f;
    }
    __syncthreads();
    const int jl = threadIdx.x & 63;
    const int i  = threadIdx.x >> 6;
    const int j  = jb + jl;
    const float* xr = xs + i * HID;
    const float* hr = hs + i * HID;
    float cx0 = 0.f, cx1 = 0.f, ch0 = 0.f, ch1 = 0.f;
    #pragma unroll 8
    for (int k = 0; k < 512; ++k) {
        cx0 = __builtin_fmaf(xr[k], Wih[(size_t)k * HID + j], cx0);
        ch0 = __builtin_fmaf(hr[k], Whh[(size_t)k * HID + j], ch0);
    }
    #pragma unroll 8
    for (int k = 512; k < 1024; ++k) {
        cx1 = __builtin_fmaf(xr[k], Wih[(size_t)k * HID + j], cx1);
        ch1 = __builtin_fmaf(hr[k], Whh[(size_t)k * HID + j], ch1);
    }
    const float s = (cx0 + cx1) + (ch0 + ch1);
    hout[(size_t)(ib + i) * HID + j] = tanh_T2(s);
}

extern "C" void kernel_launch(void* const* d_in, const int* in_sizes, int n_in,
                              void* d_out, int out_size, void* d_ws, size_t ws_size,
                              hipStream_t stream) {
    const float* x   = (const float*)d_in[0];
    const float* Wih = (const float*)d_in[1];
    const float* Whh = (const float*)d_in[2];
    float* out = (float*)d_out;

    const size_t wT  = (size_t)HID * HID;                 // floats per WT
    const size_t need = (2 * wT + 2 * (size_t)NELEM) * sizeof(float)
                      + 8 * 32 * sizeof(unsigned int);    // ~8.5 MB
    if (ws_size >= need) {
        float* WTih = (float*)d_ws;
        float* WThh = WTih + wT;
        float* hb0  = WThh + wT;
        float* hb1  = hb0 + NELEM;
        unsigned int* cnt = (unsigned int*)(hb1 + NELEM);

        transpose_w<<<dim3(16, 16), 256, 0, stream>>>(Wih, WTih);
        transpose_w<<<dim3(16, 16), 256, 0, stream>>>(Whh, WThh);
        hipMemsetAsync(cnt, 0, 8 * 32 * sizeof(unsigned int), stream);

        rnn_persist2<<<dim3(512), dim3(256), 0, stream>>>(
            x, WTih, WThh, hb0, hb1, cnt, out);
    } else {
        float* buf0 = (float*)d_ws;
        float* buf1 = buf0 + NELEM;
        const dim3 grid(HID / 64, BATCH / 4), block(256);
        for (int t = 0; t < TSTEPS; ++t) {
            const float* hin = (t == 0) ? nullptr
                              : ((t & 1) ? buf0 : buf1);
            float* hout = (t == TSTEPS - 1) ? out
                         : ((t & 1) ? buf1 : buf0);
            rnn_step_r8<<<grid, block, 0, stream>>>(
                x + (size_t)t * NELEM, Wih, Whh, hin, hout);
        }
    }
}

// Round 13
// 16469.102 us; speedup vs baseline: 2.4755x; 1.2858x over previous
//
#include <hip/hip_runtime.h>

// SingleLayerRNN — Round 13: persistent kernel, fence-free IF-ordered
// coherence, per-bchunk group barriers.
//
// FROZEN arithmetic (R8, absmax=0.0):
//   cx0 = FMA chain k=0..511 of x[b,k]*Wih[k,j] (ascending, single acc)
//   cx1 = chain k=512..1023; ch0/ch1 = same over h,Whh
//   s = (cx0+cx1)+(ch0+ch1); h' = tanh_T2(s)  [XLA fast-tanh FMA form]
//
// Counter-driven deltas vs R12 (VALUBusy 12%, FETCH fixed, dur 21ms):
//  - RELAXED counter add (was RELEASE -> buffer_wbl2 L2-writeback per block
//    per step, the ~35us/step stall). Ordering: h stores are sc0sc1 (IF),
//    __syncthreads drains vmcnt(0) before the add -> IF serializes.
//  - barrier scope: per-bchunk group (64 blocks), 8 independent groups.
//  - x prefetch issued before the spin; h staged as 8B atomic loads.

#define TSTEPS 512
#define BATCH  64
#define HID    1024
#define NELEM  65536
#define LROW   1028     // LDS row stride (floats): 16B-aligned, bank-spread

__device__ __forceinline__ float tanh_T2(float x) {
#pragma clang fp contract(off)
    const float C = 7.99881172180175781f;
    float ax = fabsf(x);
    float xc = fminf(fmaxf(x, -C), C);
    float x2 = xc * xc;
    float num = -2.76076847742355e-16f;
    num = __builtin_fmaf(x2, num, 2.00018790482477e-13f);
    num = __builtin_fmaf(x2, num, -8.60467152213735e-11f);
    num = __builtin_fmaf(x2, num, 5.12229709037114e-08f);
    num = __builtin_fmaf(x2, num, 1.48572235717979e-05f);
    num = __builtin_fmaf(x2, num, 6.37261928875436e-04f);
    num = __builtin_fmaf(x2, num, 4.89352455891786e-03f);
    num = xc * num;
    float den = 1.19825839466702e-06f;
    den = __builtin_fmaf(x2, den, 1.18534705686654e-04f);
    den = __builtin_fmaf(x2, den, 2.26843463243900e-03f);
    den = __builtin_fmaf(x2, den, 4.89352518554385e-03f);
    float r = num / den;
    return (ax < 0.0004f) ? x : r;
}

// W [k][j] -> WT [j][k]  (bit-exact data movement; verified in R10/R12)
__global__ __launch_bounds__(256) void transpose_w(const float* __restrict__ W,
                                                   float* __restrict__ WT) {
    __shared__ float tile[64][65];
    const int c0 = blockIdx.x * 64;
    const int r0 = blockIdx.y * 64;
    const int tx = threadIdx.x & 63;
    const int ty = threadIdx.x >> 6;
    #pragma unroll
    for (int r = 0; r < 16; ++r) {
        const int rr = r * 4 + ty;
        tile[rr][tx] = W[(size_t)(r0 + rr) * HID + c0 + tx];
    }
    __syncthreads();
    #pragma unroll
    for (int r = 0; r < 16; ++r) {
        const int rr = r * 4 + ty;
        WT[(size_t)(c0 + rr) * HID + r0 + tx] = tile[tx][rr];
    }
}

__global__ __launch_bounds__(256, 2) void rnn_persist3(
    const float* __restrict__ x,      // [512][64][1024]
    const float* __restrict__ WTih,   // [j][k]
    const float* __restrict__ WThh,   // [j][k]
    float* __restrict__ hb0,
    float* __restrict__ hb1,
    unsigned int* __restrict__ cnt,   // 8 group counters, 128B apart
    float* __restrict__ out)
{
#pragma clang fp contract(off)
    __shared__ float lds_x[8 * LROW];
    __shared__ float lds_h[8 * LROW];
    __shared__ float pl[4][8][16];    // [mat*2+half][b][j]

    const int slice  = blockIdx.x & 7;     // j-slice -> XCD (round-robin)
    const int wid    = blockIdx.x >> 3;    // 0..63
    const int bchunk = wid >> 3;           // 0..7  (8 batch rows each)
    const int jchunk = wid & 7;            // 0..7  (16 j cols each)
    const int tid  = threadIdx.x;
    const int jl   = tid & 15;
    const int bp   = (tid >> 4) & 3;
    const int half = (tid >> 6) & 1;
    const int mat  = tid >> 7;             // wave-uniform
    const int jglob = slice * 128 + jchunk * 16 + jl;
    const int b0 = 2 * bp;

    const float* wrow = ((mat == 0) ? WTih : WThh)
                      + (size_t)jglob * HID + half * 512;
    float* hb[2] = { hb0, hb1 };
    unsigned int* mycnt = &cnt[bchunk * 32];

    for (int t = 0; t < TSTEPS; ++t) {
        // ---- prefetch x_t into registers (independent of h_t) ----
        float4 xv[8];
        {
            const float* xsrc = x + (size_t)t * NELEM
                              + (size_t)(bchunk * 8) * HID;
            #pragma unroll
            for (int u = 0; u < 8; ++u) {
                const int i = tid + u * 256;
                const int r = i >> 8, c4 = i & 255;
                xv[u] = ((const float4*)(xsrc + (size_t)r * HID))[c4];
            }
        }

        // ---- group barrier: wait for all 64 group blocks at step t ----
        if (t > 0) {
            if (tid == 0) {
                const unsigned target = 64u * (unsigned)t;
                while (__hip_atomic_load(mycnt, __ATOMIC_RELAXED,
                                         __HIP_MEMORY_SCOPE_SYSTEM) < target)
                    __builtin_amdgcn_s_sleep(1);
            }
            __syncthreads();
        }

        // ---- stage: x (registers->LDS), h (IF-point 8B loads ->LDS) ----
        #pragma unroll
        for (int u = 0; u < 8; ++u) {
            const int i = tid + u * 256;
            const int r = i >> 8, c4 = i & 255;
            *(float4*)&lds_x[r * LROW + c4 * 4] = xv[u];
        }
        if (t > 0) {
            const unsigned long long* hsrc = (const unsigned long long*)
                (hb[t & 1] + (size_t)(bchunk * 8) * HID);
            unsigned long long hv[16];
            #pragma unroll
            for (int u = 0; u < 16; ++u) {
                const int i = tid + u * 256;       // qword 0..4095
                const int r = i >> 9, kq = i & 511;
                hv[u] = __hip_atomic_load(&hsrc[(size_t)r * 512 + kq],
                                          __ATOMIC_RELAXED,
                                          __HIP_MEMORY_SCOPE_SYSTEM);
            }
            #pragma unroll
            for (int u = 0; u < 16; ++u) {
                const int i = tid + u * 256;
                const int r = i >> 9, k = (i & 511) * 2;
                float2 f2;
                f2.x = __uint_as_float((unsigned)(hv[u] & 0xFFFFFFFFull));
                f2.y = __uint_as_float((unsigned)(hv[u] >> 32));
                *(float2*)&lds_h[r * LROW + k] = f2;
            }
        }
        __syncthreads();

        // ---- chains (frozen order; two b-rows share each W value) ----
        float acc0 = 0.0f, acc1 = 0.0f;
        if (mat == 0 || t > 0) {
            const float* base = (mat == 0) ? lds_x : lds_h;
            const float* oa = base + b0 * LROW;
            const float* ob = base + (b0 + 1) * LROW;
            const float4* w4 = (const float4*)wrow;
            const int kbase = half * 512;
            #pragma unroll 4
            for (int kq = 0; kq < 128; ++kq) {
                const float4 w = w4[kq];
                const int k = kbase + kq * 4;
                acc0 = __builtin_fmaf(oa[k + 0], w.x, acc0);
                acc1 = __builtin_fmaf(ob[k + 0], w.x, acc1);
                acc0 = __builtin_fmaf(oa[k + 1], w.y, acc0);
                acc1 = __builtin_fmaf(ob[k + 1], w.y, acc1);
                acc0 = __builtin_fmaf(oa[k + 2], w.z, acc0);
                acc1 = __builtin_fmaf(ob[k + 2], w.z, acc1);
                acc0 = __builtin_fmaf(oa[k + 3], w.w, acc0);
                acc1 = __builtin_fmaf(ob[k + 3], w.w, acc1);
            }
        }
        pl[mat * 2 + half][b0][jl]     = acc0;
        pl[mat * 2 + half][b0 + 1][jl] = acc1;
        __syncthreads();

        // ---- combine (frozen order) + publish h_{t+1} ----
        if (tid < 128) {
            const int b = tid >> 4, j = tid & 15;
            const float dotX = pl[0][b][j] + pl[1][b][j];   // cx0 + cx1
            const float dotH = pl[2][b][j] + pl[3][b][j];   // ch0 + ch1
            const float hv = tanh_T2(dotX + dotH);
            const size_t o = (size_t)(bchunk * 8 + b) * HID
                           + (size_t)slice * 128 + (size_t)jchunk * 16 + j;
            if (t + 1 < TSTEPS)
                __hip_atomic_store(&hb[(t + 1) & 1][o], hv, __ATOMIC_RELAXED,
                                   __HIP_MEMORY_SCOPE_SYSTEM);
            else
                out[o] = hv;
        }
        __syncthreads();   // vmcnt(0): h stores complete at IF before arrival

        // ---- publish arrival: RELAXED (no wbl2). IF orders add after stores.
        if (t + 1 < TSTEPS && tid == 0)
            __hip_atomic_fetch_add(mycnt, 1u, __ATOMIC_RELAXED,
                                   __HIP_MEMORY_SCOPE_SYSTEM);
    }
}

// ---- proven fallback (R8): 512 launches, 512KB ws ----
__global__ __launch_bounds__(256) void rnn_step_r8(
    const float* __restrict__ xt, const float* __restrict__ Wih,
    const float* __restrict__ Whh, const float* __restrict__ hin,
    float* __restrict__ hout)
{
#pragma clang fp contract(off)
    __shared__ float xs[4 * HID];
    __shared__ float hs[4 * HID];
    const int jb = blockIdx.x * 64;
    const int ib = blockIdx.y * 4;
    for (int idx = threadIdx.x; idx < 4 * HID; idx += 256) {
        xs[idx] = xt[ib * HID + idx];
        hs[idx] = hin ? hin[ib * HID + idx] : 0.0f;
    }
    __syncthreads();
    const int jl = threadIdx.x & 63;
    const int i  = threadIdx.x >> 6;
    const int j  = jb + jl;
    const float* xr = xs + i * HID;
    const float* hr = hs + i * HID;
    float cx0 = 0.f, cx1 = 0.f, ch0 = 0.f, ch1 = 0.f;
    #pragma unroll 8
    for (int k = 0; k < 512; ++k) {
        cx0 = __builtin_fmaf(xr[k], Wih[(size_t)k * HID + j], cx0);
        ch0 = __builtin_fmaf(hr[k], Whh[(size_t)k * HID + j], ch0);
    }
    #pragma unroll 8
    for (int k = 512; k < 1024; ++k) {
        cx1 = __builtin_fmaf(xr[k], Wih[(size_t)k * HID + j], cx1);
        ch1 = __builtin_fmaf(hr[k], Whh[(size_t)k * HID + j], ch1);
    }
    const float s = (cx0 + cx1) + (ch0 + ch1);
    hout[(size_t)(ib + i) * HID + j] = tanh_T2(s);
}

extern "C" void kernel_launch(void* const* d_in, const int* in_sizes, int n_in,
                              void* d_out, int out_size, void* d_ws, size_t ws_size,
                              hipStream_t stream) {
    const float* x   = (const float*)d_in[0];
    const float* Wih = (const float*)d_in[1];
    const float* Whh = (const float*)d_in[2];
    float* out = (float*)d_out;

    const size_t wT = (size_t)HID * HID;
    const size_t need = (2 * wT + 2 * (size_t)NELEM) * sizeof(float)
                      + 8 * 32 * sizeof(unsigned int);    // ~8.5 MB
    if (ws_size >= need) {
        float* WTih = (float*)d_ws;
        float* WThh = WTih + wT;
        float* hb0  = WThh + wT;
        float* hb1  = hb0 + NELEM;
        unsigned int* cnt = (unsigned int*)(hb1 + NELEM);

        transpose_w<<<dim3(16, 16), 256, 0, stream>>>(Wih, WTih);
        transpose_w<<<dim3(16, 16), 256, 0, stream>>>(Whh, WThh);
        hipMemsetAsync(cnt, 0, 8 * 32 * sizeof(unsigned int), stream);

        rnn_persist3<<<dim3(512), dim3(256), 0, stream>>>(
            x, WTih, WThh, hb0, hb1, cnt, out);
    } else {
        float* buf0 = (float*)d_ws;
        float* buf1 = buf0 + NELEM;
        const dim3 grid(HID / 64, BATCH / 4), block(256);
        for (int t = 0; t < TSTEPS; ++t) {
            const float* hin = (t == 0) ? nullptr
                              : ((t & 1) ? buf0 : buf1);
            float* hout = (t == TSTEPS - 1) ? out
                         : ((t & 1) ? buf1 : buf0);
            rnn_step_r8<<<grid, block, 0, stream>>>(
                x + (size_t)t * NELEM, Wih, Whh, hin, hout);
        }
    }
}

// Round 14
// 16391.902 us; speedup vs baseline: 2.4872x; 1.0047x over previous
//
#include <hip/hip_runtime.h>

// SingleLayerRNN — Round 14: persistent kernel; RELAXED publish + 32-bit
// IF-point h reads (completes the R12/R13 2x2 factor isolation).
//
// FROZEN arithmetic (R8, absmax=0.0):
//   cx0 = FMA chain k=0..511 of x[b,k]*Wih[k,j] (ascending, single acc)
//   cx1 = chain k=512..1023; ch0/ch1 = same over h,Whh
//   s = (cx0+cx1)+(ch0+ch1); h' = tanh_T2(s)  [XLA fast-tanh FMA form]
//
// Counter evidence:
//  R12 (RELEASE add + 32b loads): 21ms — wbl2 L2-writeback per block/step.
//  R13 (RELAXED add + 64b loads): 16.5ms — 64b atomic load lowers to RMW,
//       WRITE_SIZE 8.46GB/dispatch of IF write-through.
//  R14: RELAXED add + 32b loads. Publish side proven by R13, consume side
//       proven by R12 (both absmax 0.0).

#define TSTEPS 512
#define BATCH  64
#define HID    1024
#define NELEM  65536
#define LROW   1028     // LDS row stride (floats): 16B-aligned, bank-spread

__device__ __forceinline__ float tanh_T2(float x) {
#pragma clang fp contract(off)
    const float C = 7.99881172180175781f;
    float ax = fabsf(x);
    float xc = fminf(fmaxf(x, -C), C);
    float x2 = xc * xc;
    float num = -2.76076847742355e-16f;
    num = __builtin_fmaf(x2, num, 2.00018790482477e-13f);
    num = __builtin_fmaf(x2, num, -8.60467152213735e-11f);
    num = __builtin_fmaf(x2, num, 5.12229709037114e-08f);
    num = __builtin_fmaf(x2, num, 1.48572235717979e-05f);
    num = __builtin_fmaf(x2, num, 6.37261928875436e-04f);
    num = __builtin_fmaf(x2, num, 4.89352455891786e-03f);
    num = xc * num;
    float den = 1.19825839466702e-06f;
    den = __builtin_fmaf(x2, den, 1.18534705686654e-04f);
    den = __builtin_fmaf(x2, den, 2.26843463243900e-03f);
    den = __builtin_fmaf(x2, den, 4.89352518554385e-03f);
    float r = num / den;
    return (ax < 0.0004f) ? x : r;
}

// W [k][j] -> WT [j][k]  (bit-exact data movement; verified R10/R12/R13)
__global__ __launch_bounds__(256) void transpose_w(const float* __restrict__ W,
                                                   float* __restrict__ WT) {
    __shared__ float tile[64][65];
    const int c0 = blockIdx.x * 64;
    const int r0 = blockIdx.y * 64;
    const int tx = threadIdx.x & 63;
    const int ty = threadIdx.x >> 6;
    #pragma unroll
    for (int r = 0; r < 16; ++r) {
        const int rr = r * 4 + ty;
        tile[rr][tx] = W[(size_t)(r0 + rr) * HID + c0 + tx];
    }
    __syncthreads();
    #pragma unroll
    for (int r = 0; r < 16; ++r) {
        const int rr = r * 4 + ty;
        WT[(size_t)(c0 + rr) * HID + r0 + tx] = tile[tx][rr];
    }
}

__global__ __launch_bounds__(256, 2) void rnn_persist4(
    const float* __restrict__ x,      // [512][64][1024]
    const float* __restrict__ WTih,   // [j][k]
    const float* __restrict__ WThh,   // [j][k]
    float* __restrict__ hb0,
    float* __restrict__ hb1,
    unsigned int* __restrict__ cnt,   // 8 group counters, 128B apart
    float* __restrict__ out)
{
#pragma clang fp contract(off)
    __shared__ float lds_x[8 * LROW];
    __shared__ float lds_h[8 * LROW];
    __shared__ float pl[4][8][16];    // [mat*2+half][b][j]

    const int slice  = blockIdx.x & 7;     // j-slice -> XCD (round-robin)
    const int wid    = blockIdx.x >> 3;    // 0..63
    const int bchunk = wid >> 3;           // 0..7  (8 batch rows each)
    const int jchunk = wid & 7;            // 0..7  (16 j cols each)
    const int tid  = threadIdx.x;
    const int jl   = tid & 15;
    const int bp   = (tid >> 4) & 3;
    const int half = (tid >> 6) & 1;
    const int mat  = tid >> 7;             // wave-uniform
    const int jglob = slice * 128 + jchunk * 16 + jl;
    const int b0 = 2 * bp;

    const float* wrow = ((mat == 0) ? WTih : WThh)
                      + (size_t)jglob * HID + half * 512;
    float* hb[2] = { hb0, hb1 };
    unsigned int* mycnt = &cnt[bchunk * 32];

    for (int t = 0; t < TSTEPS; ++t) {
        // ---- prefetch x_t into registers (independent of h_t) ----
        float4 xv[8];
        {
            const float* xsrc = x + (size_t)t * NELEM
                              + (size_t)(bchunk * 8) * HID;
            #pragma unroll
            for (int u = 0; u < 8; ++u) {
                const int i = tid + u * 256;
                const int r = i >> 8, c4 = i & 255;
                xv[u] = ((const float4*)(xsrc + (size_t)r * HID))[c4];
            }
        }

        // ---- group barrier: all 64 blocks of this bchunk at step t ----
        if (t > 0) {
            if (tid == 0) {
                const unsigned target = 64u * (unsigned)t;
                while (__hip_atomic_load(mycnt, __ATOMIC_RELAXED,
                                         __HIP_MEMORY_SCOPE_SYSTEM) < target)
                    __builtin_amdgcn_s_sleep(1);
            }
            __syncthreads();
        }

        // ---- stage: x regs->LDS; h via 32-bit IF-point loads ->LDS ----
        #pragma unroll
        for (int u = 0; u < 8; ++u) {
            const int i = tid + u * 256;
            const int r = i >> 8, c4 = i & 255;
            *(float4*)&lds_x[r * LROW + c4 * 4] = xv[u];
        }
        if (t > 0) {
            const float* hsrc = hb[t & 1] + (size_t)(bchunk * 8) * HID;
            for (int blk = 0; blk < 4; ++blk) {
                float hv[8];
                #pragma unroll
                for (int u = 0; u < 8; ++u) {
                    const int i = tid + (blk * 8 + u) * 256;   // dword 0..8191
                    const int r = i >> 10, k = i & 1023;
                    hv[u] = __hip_atomic_load(&hsrc[(size_t)r * HID + k],
                                              __ATOMIC_RELAXED,
                                              __HIP_MEMORY_SCOPE_SYSTEM);
                }
                #pragma unroll
                for (int u = 0; u < 8; ++u) {
                    const int i = tid + (blk * 8 + u) * 256;
                    const int r = i >> 10, k = i & 1023;
                    lds_h[r * LROW + k] = hv[u];
                }
            }
        }
        __syncthreads();

        // ---- chains (frozen order; two b-rows share each W value) ----
        float acc0 = 0.0f, acc1 = 0.0f;
        if (mat == 0 || t > 0) {
            const float* base = (mat == 0) ? lds_x : lds_h;
            const float* oa = base + b0 * LROW;
            const float* ob = base + (b0 + 1) * LROW;
            const float4* w4 = (const float4*)wrow;
            const int kbase = half * 512;
            #pragma unroll 4
            for (int kq = 0; kq < 128; ++kq) {
                const float4 w = w4[kq];
                const int k = kbase + kq * 4;
                acc0 = __builtin_fmaf(oa[k + 0], w.x, acc0);
                acc1 = __builtin_fmaf(ob[k + 0], w.x, acc1);
                acc0 = __builtin_fmaf(oa[k + 1], w.y, acc0);
                acc1 = __builtin_fmaf(ob[k + 1], w.y, acc1);
                acc0 = __builtin_fmaf(oa[k + 2], w.z, acc0);
                acc1 = __builtin_fmaf(ob[k + 2], w.z, acc1);
                acc0 = __builtin_fmaf(oa[k + 3], w.w, acc0);
                acc1 = __builtin_fmaf(ob[k + 3], w.w, acc1);
            }
        }
        pl[mat * 2 + half][b0][jl]     = acc0;
        pl[mat * 2 + half][b0 + 1][jl] = acc1;
        __syncthreads();

        // ---- combine (frozen order) + publish h_{t+1} ----
        if (tid < 128) {
            const int b = tid >> 4, j = tid & 15;
            const float dotX = pl[0][b][j] + pl[1][b][j];   // cx0 + cx1
            const float dotH = pl[2][b][j] + pl[3][b][j];   // ch0 + ch1
            const float hv = tanh_T2(dotX + dotH);
            const size_t o = (size_t)(bchunk * 8 + b) * HID
                           + (size_t)slice * 128 + (size_t)jchunk * 16 + j;
            if (t + 1 < TSTEPS)
                __hip_atomic_store(&hb[(t + 1) & 1][o], hv, __ATOMIC_RELAXED,
                                   __HIP_MEMORY_SCOPE_SYSTEM);
            else
                out[o] = hv;
        }
        __syncthreads();   // vmcnt(0): h stores complete at IF before arrival

        // ---- publish arrival: RELAXED add (no wbl2; IF orders after stores)
        if (t + 1 < TSTEPS && tid == 0)
            __hip_atomic_fetch_add(mycnt, 1u, __ATOMIC_RELAXED,
                                   __HIP_MEMORY_SCOPE_SYSTEM);
    }
}

// ---- proven fallback (R8): 512 launches, 512KB ws ----
__global__ __launch_bounds__(256) void rnn_step_r8(
    const float* __restrict__ xt, const float* __restrict__ Wih,
    const float* __restrict__ Whh, const float* __restrict__ hin,
    float* __restrict__ hout)
{
#pragma clang fp contract(off)
    __shared__ float xs[4 * HID];
    __shared__ float hs[4 * HID];
    const int jb = blockIdx.x * 64;
    const int ib = blockIdx.y * 4;
    for (int idx = threadIdx.x; idx < 4 * HID; idx += 256) {
        xs[idx] = xt[ib * HID + idx];
        hs[idx] = hin ? hin[ib * HID + idx] : 0.0f;
    }
    __syncthreads();
    const int jl = threadIdx.x & 63;
    const int i  = threadIdx.x >> 6;
    const int j  = jb + jl;
    const float* xr = xs + i * HID;
    const float* hr = hs + i * HID;
    float cx0 = 0.f, cx1 = 0.f, ch0 = 0.f, ch1 = 0.f;
    #pragma unroll 8
    for (int k = 0; k < 512; ++k) {
        cx0 = __builtin_fmaf(xr[k], Wih[(size_t)k * HID + j], cx0);
        ch0 = __builtin_fmaf(hr[k], Whh[(size_t)k * HID + j], ch0);
    }
    #pragma unroll 8
    for (int k = 512; k < 1024; ++k) {
        cx1 = __builtin_fmaf(xr[k], Wih[(size_t)k * HID + j], cx1);
        ch1 = __builtin_fmaf(hr[k], Whh[(size_t)k * HID + j], ch1);
    }
    const float s = (cx0 + cx1) + (ch0 + ch1);
    hout[(size_t)(ib + i) * HID + j] = tanh_T2(s);
}

extern "C" void kernel_launch(void* const* d_in, const int* in_sizes, int n_in,
                              void* d_out, int out_size, void* d_ws, size_t ws_size,
                              hipStream_t stream) {
    const float* x   = (const float*)d_in[0];
    const float* Wih = (const float*)d_in[1];
    const float* Whh = (const float*)d_in[2];
    float* out = (float*)d_out;

    const size_t wT = (size_t)HID * HID;
    const size_t need = (2 * wT + 2 * (size_t)NELEM) * sizeof(float)
                      + 8 * 32 * sizeof(unsigned int);    // ~8.5 MB
    if (ws_size >= need) {
        float* WTih = (float*)d_ws;
        float* WThh = WTih + wT;
        float* hb0  = WThh + wT;
        float* hb1  = hb0 + NELEM;
        unsigned int* cnt = (unsigned int*)(hb1 + NELEM);

        transpose_w<<<dim3(16, 16), 256, 0, stream>>>(Wih, WTih);
        transpose_w<<<dim3(16, 16), 256, 0, stream>>>(Whh, WThh);
        hipMemsetAsync(cnt, 0, 8 * 32 * sizeof(unsigned int), stream);

        rnn_persist4<<<dim3(512), dim3(256), 0, stream>>>(
            x, WTih, WThh, hb0, hb1, cnt, out);
    } else {
        float* buf0 = (float*)d_ws;
        float* buf1 = buf0 + NELEM;
        const dim3 grid(HID / 64, BATCH / 4), block(256);
        for (int t = 0; t < TSTEPS; ++t) {
            const float* hin = (t == 0) ? nullptr
                              : ((t & 1) ? buf0 : buf1);
            float* hout = (t == TSTEPS - 1) ? out
                         : ((t & 1) ? buf1 : buf0);
            rnn_step_r8<<<grid, block, 0, stream>>>(
                x + (size_t)t * NELEM, Wih, Whh, hin, hout);
        }
    }
}

// Round 15
// 16268.440 us; speedup vs baseline: 2.5061x; 1.0076x over previous
//
#include <hip/hip_runtime.h>

// SingleLayerRNN — Round 15: single-variable experiment — h/cnt exchange
// scope SYSTEM -> AGENT (device). R14 evidence: system-scope ops route to the
// host-coherent point (HBM), showing as 8.46GB WRITE (atomics use the EA
// write path) and ~84% stall. Agent scope is serviced at the MALL (shared by
// all 8 XCDs; per-XCD L2 bypassed via sc1) — sufficient for cross-XCD
// correctness per guide G12. Everything else byte-identical to R14.
//
// FROZEN arithmetic (R8, absmax=0.0):
//   cx0 = FMA chain k=0..511 of x[b,k]*Wih[k,j] (ascending, single acc)
//   cx1 = chain k=512..1023; ch0/ch1 = same over h,Whh
//   s = (cx0+cx1)+(ch0+ch1); h' = tanh_T2(s)  [XLA fast-tanh FMA form]

#define TSTEPS 512
#define BATCH  64
#define HID    1024
#define NELEM  65536
#define LROW   1028     // LDS row stride (floats): 16B-aligned, bank-spread

__device__ __forceinline__ float tanh_T2(float x) {
#pragma clang fp contract(off)
    const float C = 7.99881172180175781f;
    float ax = fabsf(x);
    float xc = fminf(fmaxf(x, -C), C);
    float x2 = xc * xc;
    float num = -2.76076847742355e-16f;
    num = __builtin_fmaf(x2, num, 2.00018790482477e-13f);
    num = __builtin_fmaf(x2, num, -8.60467152213735e-11f);
    num = __builtin_fmaf(x2, num, 5.12229709037114e-08f);
    num = __builtin_fmaf(x2, num, 1.48572235717979e-05f);
    num = __builtin_fmaf(x2, num, 6.37261928875436e-04f);
    num = __builtin_fmaf(x2, num, 4.89352455891786e-03f);
    num = xc * num;
    float den = 1.19825839466702e-06f;
    den = __builtin_fmaf(x2, den, 1.18534705686654e-04f);
    den = __builtin_fmaf(x2, den, 2.26843463243900e-03f);
    den = __builtin_fmaf(x2, den, 4.89352518554385e-03f);
    float r = num / den;
    return (ax < 0.0004f) ? x : r;
}

// W [k][j] -> WT [j][k]  (bit-exact data movement; verified R10/R12-R14)
__global__ __launch_bounds__(256) void transpose_w(const float* __restrict__ W,
                                                   float* __restrict__ WT) {
    __shared__ float tile[64][65];
    const int c0 = blockIdx.x * 64;
    const int r0 = blockIdx.y * 64;
    const int tx = threadIdx.x & 63;
    const int ty = threadIdx.x >> 6;
    #pragma unroll
    for (int r = 0; r < 16; ++r) {
        const int rr = r * 4 + ty;
        tile[rr][tx] = W[(size_t)(r0 + rr) * HID + c0 + tx];
    }
    __syncthreads();
    #pragma unroll
    for (int r = 0; r < 16; ++r) {
        const int rr = r * 4 + ty;
        WT[(size_t)(c0 + rr) * HID + r0 + tx] = tile[tx][rr];
    }
}

__global__ __launch_bounds__(256, 2) void rnn_persist5(
    const float* __restrict__ x,      // [512][64][1024]
    const float* __restrict__ WTih,   // [j][k]
    const float* __restrict__ WThh,   // [j][k]
    float* __restrict__ hb0,
    float* __restrict__ hb1,
    unsigned int* __restrict__ cnt,   // 8 group counters, 128B apart
    float* __restrict__ out)
{
#pragma clang fp contract(off)
    __shared__ float lds_x[8 * LROW];
    __shared__ float lds_h[8 * LROW];
    __shared__ float pl[4][8][16];    // [mat*2+half][b][j]

    const int slice  = blockIdx.x & 7;     // j-slice -> XCD (round-robin)
    const int wid    = blockIdx.x >> 3;    // 0..63
    const int bchunk = wid >> 3;           // 0..7  (8 batch rows each)
    const int jchunk = wid & 7;            // 0..7  (16 j cols each)
    const int tid  = threadIdx.x;
    const int jl   = tid & 15;
    const int bp   = (tid >> 4) & 3;
    const int half = (tid >> 6) & 1;
    const int mat  = tid >> 7;             // wave-uniform
    const int jglob = slice * 128 + jchunk * 16 + jl;
    const int b0 = 2 * bp;

    const float* wrow = ((mat == 0) ? WTih : WThh)
                      + (size_t)jglob * HID + half * 512;
    float* hb[2] = { hb0, hb1 };
    unsigned int* mycnt = &cnt[bchunk * 32];

    for (int t = 0; t < TSTEPS; ++t) {
        // ---- prefetch x_t into registers (independent of h_t) ----
        float4 xv[8];
        {
            const float* xsrc = x + (size_t)t * NELEM
                              + (size_t)(bchunk * 8) * HID;
            #pragma unroll
            for (int u = 0; u < 8; ++u) {
                const int i = tid + u * 256;
                const int r = i >> 8, c4 = i & 255;
                xv[u] = ((const float4*)(xsrc + (size_t)r * HID))[c4];
            }
        }

        // ---- group barrier: all 64 blocks of this bchunk at step t ----
        if (t > 0) {
            if (tid == 0) {
                const unsigned target = 64u * (unsigned)t;
                while (__hip_atomic_load(mycnt, __ATOMIC_RELAXED,
                                         __HIP_MEMORY_SCOPE_AGENT) < target)
                    __builtin_amdgcn_s_sleep(1);
            }
            __syncthreads();
        }

        // ---- stage: x regs->LDS; h via 32-bit device-scope loads ->LDS ----
        #pragma unroll
        for (int u = 0; u < 8; ++u) {
            const int i = tid + u * 256;
            const int r = i >> 8, c4 = i & 255;
            *(float4*)&lds_x[r * LROW + c4 * 4] = xv[u];
        }
        if (t > 0) {
            const float* hsrc = hb[t & 1] + (size_t)(bchunk * 8) * HID;
            for (int blk = 0; blk < 4; ++blk) {
                float hv[8];
                #pragma unroll
                for (int u = 0; u < 8; ++u) {
                    const int i = tid + (blk * 8 + u) * 256;   // dword 0..8191
                    const int r = i >> 10, k = i & 1023;
                    hv[u] = __hip_atomic_load(&hsrc[(size_t)r * HID + k],
                                              __ATOMIC_RELAXED,
                                              __HIP_MEMORY_SCOPE_AGENT);
                }
                #pragma unroll
                for (int u = 0; u < 8; ++u) {
                    const int i = tid + (blk * 8 + u) * 256;
                    const int r = i >> 10, k = i & 1023;
                    lds_h[r * LROW + k] = hv[u];
                }
            }
        }
        __syncthreads();

        // ---- chains (frozen order; two b-rows share each W value) ----
        float acc0 = 0.0f, acc1 = 0.0f;
        if (mat == 0 || t > 0) {
            const float* base = (mat == 0) ? lds_x : lds_h;
            const float* oa = base + b0 * LROW;
            const float* ob = base + (b0 + 1) * LROW;
            const float4* w4 = (const float4*)wrow;
            const int kbase = half * 512;
            #pragma unroll 4
            for (int kq = 0; kq < 128; ++kq) {
                const float4 w = w4[kq];
                const int k = kbase + kq * 4;
                acc0 = __builtin_fmaf(oa[k + 0], w.x, acc0);
                acc1 = __builtin_fmaf(ob[k + 0], w.x, acc1);
                acc0 = __builtin_fmaf(oa[k + 1], w.y, acc0);
                acc1 = __builtin_fmaf(ob[k + 1], w.y, acc1);
                acc0 = __builtin_fmaf(oa[k + 2], w.z, acc0);
                acc1 = __builtin_fmaf(ob[k + 2], w.z, acc1);
                acc0 = __builtin_fmaf(oa[k + 3], w.w, acc0);
                acc1 = __builtin_fmaf(ob[k + 3], w.w, acc1);
            }
        }
        pl[mat * 2 + half][b0][jl]     = acc0;
        pl[mat * 2 + half][b0 + 1][jl] = acc1;
        __syncthreads();

        // ---- combine (frozen order) + publish h_{t+1} ----
        if (tid < 128) {
            const int b = tid >> 4, j = tid & 15;
            const float dotX = pl[0][b][j] + pl[1][b][j];   // cx0 + cx1
            const float dotH = pl[2][b][j] + pl[3][b][j];   // ch0 + ch1
            const float hv = tanh_T2(dotX + dotH);
            const size_t o = (size_t)(bchunk * 8 + b) * HID
                           + (size_t)slice * 128 + (size_t)jchunk * 16 + j;
            if (t + 1 < TSTEPS)
                __hip_atomic_store(&hb[(t + 1) & 1][o], hv, __ATOMIC_RELAXED,
                                   __HIP_MEMORY_SCOPE_AGENT);
            else
                out[o] = hv;
        }
        __syncthreads();   // vmcnt(0): h stores complete at MALL before arrival

        // ---- publish arrival: relaxed device-scope add ----
        if (t + 1 < TSTEPS && tid == 0)
            __hip_atomic_fetch_add(mycnt, 1u, __ATOMIC_RELAXED,
                                   __HIP_MEMORY_SCOPE_AGENT);
    }
}

// ---- proven fallback (R8): 512 launches, 512KB ws ----
__global__ __launch_bounds__(256) void rnn_step_r8(
    const float* __restrict__ xt, const float* __restrict__ Wih,
    const float* __restrict__ Whh, const float* __restrict__ hin,
    float* __restrict__ hout)
{
#pragma clang fp contract(off)
    __shared__ float xs[4 * HID];
    __shared__ float hs[4 * HID];
    const int jb = blockIdx.x * 64;
    const int ib = blockIdx.y * 4;
    for (int idx = threadIdx.x; idx < 4 * HID; idx += 256) {
        xs[idx] = xt[ib * HID + idx];
        hs[idx] = hin ? hin[ib * HID + idx] : 0.0f;
    }
    __syncthreads();
    const int jl = threadIdx.x & 63;
    const int i  = threadIdx.x >> 6;
    const int j  = jb + jl;
    const float* xr = xs + i * HID;
    const float* hr = hs + i * HID;
    float cx0 = 0.f, cx1 = 0.f, ch0 = 0.f, ch1 = 0.f;
    #pragma unroll 8
    for (int k = 0; k < 512; ++k) {
        cx0 = __builtin_fmaf(xr[k], Wih[(size_t)k * HID + j], cx0);
        ch0 = __builtin_fmaf(hr[k], Whh[(size_t)k * HID + j], ch0);
    }
    #pragma unroll 8
    for (int k = 512; k < 1024; ++k) {
        cx1 = __builtin_fmaf(xr[k], Wih[(size_t)k * HID + j], cx1);
        ch1 = __builtin_fmaf(hr[k], Whh[(size_t)k * HID + j], ch1);
    }
    const float s = (cx0 + cx1) + (ch0 + ch1);
    hout[(size_t)(ib + i) * HID + j] = tanh_T2(s);
}

extern "C" void kernel_launch(void* const* d_in, const int* in_sizes, int n_in,
                              void* d_out, int out_size, void* d_ws, size_t ws_size,
                              hipStream_t stream) {
    const float* x   = (const float*)d_in[0];
    const float* Wih = (const float*)d_in[1];
    const float* Whh = (const float*)d_in[2];
    float* out = (float*)d_out;

    const size_t wT = (size_t)HID * HID;
    const size_t need = (2 * wT + 2 * (size_t)NELEM) * sizeof(float)
                      + 8 * 32 * sizeof(unsigned int);    // ~8.5 MB
    if (ws_size >= need) {
        float* WTih = (float*)d_ws;
        float* WThh = WTih + wT;
        float* hb0  = WThh + wT;
        float* hb1  = hb0 + NELEM;
        unsigned int* cnt = (unsigned int*)(hb1 + NELEM);

        transpose_w<<<dim3(16, 16), 256, 0, stream>>>(Wih, WTih);
        transpose_w<<<dim3(16, 16), 256, 0, stream>>>(Whh, WThh);
        hipMemsetAsync(cnt, 0, 8 * 32 * sizeof(unsigned int), stream);

        rnn_persist5<<<dim3(512), dim3(256), 0, stream>>>(
            x, WTih, WThh, hb0, hb1, cnt, out);
    } else {
        float* buf0 = (float*)d_ws;
        float* buf1 = buf0 + NELEM;
        const dim3 grid(HID / 64, BATCH / 4), block(256);
        for (int t = 0; t < TSTEPS; ++t) {
            const float* hin = (t == 0) ? nullptr
                              : ((t & 1) ? buf0 : buf1);
            float* hout = (t == TSTEPS - 1) ? out
                         : ((t & 1) ? buf1 : buf0);
            rnn_step_r8<<<grid, block, 0, stream>>>(
                x + (size_t)t * NELEM, Wih, Whh, hin, hout);
        }
    }
}